// Round 7
// baseline (160.324 us; speedup 1.0000x reference)
//
#include <hip/hip_runtime.h>
#include <stdint.h>

// ---------------------------------------------------------------------------
// DetectorKmeans: out[n] = sum_k (pr[k]*var[k]) / ||X[n]-C[k]||^2  - threshold
// N=65536, K=1024, D=512, all fp32 in/out.
// Round 19: cycles are ADDITIVE across MFMA/LDS/staging pipes in every probe
// (R12-R18; R18 doubled occupancy, MfmaUtil unmoved). So shrink the summed
// work: wave tile 128x64 -> 128x128 cuts LDS-read bytes/FLOP 0.0234->0.0156
// (-33%). 4 waves of 128x128 (acc 256 f32, ~350 VGPR, 1 wave/SIMD via
// __launch_bounds__(256,1) -- free per R18). R12's LDS layout, swizzles,
// staging pattern and 1-phase schedule are VERBATIM; only the wave->tile
// mapping changes (each wave stages 2x w-slots, reads both B col-groups).
// ---------------------------------------------------------------------------

#define NR 65536
#define KC 1024
#define DD 512

#define BM 256
#define BN 256
#define BK 64
#define NKT (DD / BK)     // 8 K-tiles
#define NPART (KC / BN)   // 4 column panels

#define SLOT_SZ 65536
#define PART_OFF 131072
#define LDS_TOTAL (PART_OFF + 2048)   // + [2][256] f32 partial

typedef __bf16 bf16;
typedef __attribute__((ext_vector_type(4))) __bf16 bf16x4;
typedef __attribute__((ext_vector_type(8))) __bf16 bf16x8;
typedef __attribute__((ext_vector_type(4))) float f32x4;

__device__ __forceinline__ void gload16(const void* g, void* l) {
  __builtin_amdgcn_global_load_lds(
      (const __attribute__((address_space(1))) unsigned int*)g,
      (__attribute__((address_space(3))) unsigned int*)l, 16, 0, 0);
}

// ---------------------------------------------------------------------------
__global__ __launch_bounds__(256) void prep_kernel(
    const float* __restrict__ X, const float* __restrict__ C,
    const float* __restrict__ var, const float* __restrict__ pr,
    bf16* __restrict__ Xb, bf16* __restrict__ Cb,
    float* __restrict__ xsq, float* __restrict__ csq, float* __restrict__ w) {
  const int row  = (int)((blockIdx.x * 256 + threadIdx.x) >> 6);
  const int lane = (int)(threadIdx.x & 63);
  const bool isX = row < NR;
  const float* srow = isX ? (X + (size_t)row * DD) : (C + (size_t)(row - NR) * DD);
  bf16* drow = isX ? (Xb + (size_t)row * DD) : (Cb + (size_t)(row - NR) * DD);

  float4 a = reinterpret_cast<const float4*>(srow)[lane];
  float4 b = reinterpret_cast<const float4*>(srow)[64 + lane];
  float s = a.x * a.x + a.y * a.y + a.z * a.z + a.w * a.w +
            b.x * b.x + b.y * b.y + b.z * b.z + b.w * b.w;
#pragma unroll
  for (int off = 1; off < 64; off <<= 1) s += __shfl_xor(s, off, 64);

  bf16x4 va = {(bf16)a.x, (bf16)a.y, (bf16)a.z, (bf16)a.w};
  bf16x4 vb = {(bf16)b.x, (bf16)b.y, (bf16)b.z, (bf16)b.w};
  reinterpret_cast<bf16x4*>(drow)[lane]      = va;
  reinterpret_cast<bf16x4*>(drow)[64 + lane] = vb;

  if (lane == 0) {
    if (isX) {
      xsq[row] = s;
    } else {
      const int k = row - NR;
      csq[k] = s;
      w[k]   = pr[k] * var[k];
    }
  }
}

// ---------------------------------------------------------------------------
// LDS per 64 KB slot (verbatim R12):
//   A half h at slot + h*16384: rows {128*half + h*64 + r} at rho = 64*half+r,
//     128 B/row; chunk slot s holds global chunk s ^ (rho&7).
//   B kk at slot + 32768 + kk*16384: 256 cols x 64 B; chunk slot s holds
//     global chunk s ^ ((col>>1)&3).  Pre-swizzled gload source, linear dest.
// Staging now done by 4 waves, each covering virtual slots w=wid and w=wid+4.
// ---------------------------------------------------------------------------

#define STAGE_A(h, tn, slotW, w, aS)                                            \
  gload16(aS + (size_t)((h) * 64) * DD + (tn) * 64,                             \
          smem + (slotW) + (h) * 16384 + (w) * 1024);                           \
  gload16(aS + (size_t)((h) * 64 + 128) * DD + (tn) * 64,                       \
          smem + (slotW) + (h) * 16384 + 8192 + (w) * 1024);

#define STAGE_B(kk, tn, slotW, w, bS)                                           \
  gload16(bS + (tn) * 64 + (kk) * 32,                                           \
          smem + (slotW) + 32768 + (kk) * 16384 + (w) * 1024);                  \
  gload16(bS + (size_t)128 * DD + (tn) * 64 + (kk) * 32,                        \
          smem + (slotW) + 32768 + (kk) * 16384 + 8192 + (w) * 1024);

#define STAGE_ALL(tn, slotW)                                                    \
  STAGE_A(0, tn, slotW, wid, aSrcA);                                            \
  STAGE_A(0, tn, slotW, wid + 4, aSrcB);                                        \
  STAGE_A(1, tn, slotW, wid, aSrcA);                                            \
  STAGE_A(1, tn, slotW, wid + 4, aSrcB);                                        \
  STAGE_B(0, tn, slotW, wid, bSrcA);                                            \
  STAGE_B(0, tn, slotW, wid + 4, bSrcB);                                        \
  STAGE_B(1, tn, slotW, wid, bSrcA);                                            \
  STAGE_B(1, tn, slotW, wid + 4, bSrcB);

__global__ __launch_bounds__(256, 1) void density_kernel(
    const bf16* __restrict__ Xb, const bf16* __restrict__ Cb,
    const float* __restrict__ xsq, const float* __restrict__ csq,
    const float* __restrict__ w, float* __restrict__ partial) {
  extern __shared__ char smem[];

  const int tid  = (int)threadIdx.x;
  const int lane = tid & 63;
  const int wid  = tid >> 6;    // 0..3
  const int wr   = wid >> 1;    // 0..1 : 128-row half
  const int wcn  = wid & 1;     // 0..1 : 128-col group
  const int lr   = lane & 15;
  const int lc   = lane >> 4;

  // XCD-aware bijective swizzle: grid 1024, 8 XCDs, 128 blocks each.
  const int bid   = (int)blockIdx.x;
  const int swz   = (bid & 7) * 128 + (bid >> 3);
  const int ntile = swz >> 8;
  const int mtile = swz & 255;
  const int rowBase = mtile * BM;
  const int colBase = ntile * BN;

  // staging sources (pre-swizzled chunk; linear DMA dest) — verbatim R12
  // virtual staging slots w = wid and wid+4 (4 waves cover 8 slots)
  const bf16* aSrcA = Xb + (size_t)(rowBase + wid * 8 + (lane >> 3)) * DD +
                      (((lane & 7) ^ (lane >> 3)) << 3);
  const bf16* aSrcB = aSrcA + (size_t)32 * DD;   // (wid+4)*8 rows
  const bf16* bSrcA = Cb + (size_t)(colBase + wid * 16 + (lane >> 2)) * DD +
                      ((((lane & 3) ^ ((lane >> 3) & 3))) << 3);
  const bf16* bSrcB = bSrcA + (size_t)64 * DD;   // (wid+4)*16 cols

  // fragment read bases (same XOR on the read side) — verbatim R12
  const int aRd  = (wr * 64 + lr) * 128;
  const int aSw0 = ((lc ^ (lr & 7)) << 4);
  const int aSw1 = (((4 | lc) ^ (lr & 7)) << 4);
  const int bRd  = (wcn * 128 + lr) * 64 + ((lc ^ ((lr >> 1) & 3)) << 4);

  f32x4 acc[8][8];
#pragma unroll
  for (int m = 0; m < 8; ++m)
#pragma unroll
    for (int n = 0; n < 8; ++n) acc[m][n] = (f32x4){0.f, 0.f, 0.f, 0.f};

  // ---- prologue: stage tile 0 into slot 0 (16 gloads/wave) ----
  STAGE_ALL(0, 0);
  asm volatile("s_waitcnt vmcnt(0)");
  __builtin_amdgcn_s_barrier();

  // ---- main loop: one phase + one barrier per K-tile (R12 proven) ----
#pragma unroll 1
  for (int t = 0; t < NKT; ++t) {
    const int slotR = (t & 1) << 16;
    const int slotW = slotR ^ SLOT_SZ;
    const bool st = (t + 1) < NKT;

    if (st) { STAGE_ALL(t + 1, slotW); }

    // B fragments up front: 8 cols-tiles x 2 k-halves (64 VGPR)
    bf16x8 bgK0[8], bgK1[8];
#pragma unroll
    for (int n = 0; n < 8; ++n) {
      bgK0[n] = *(const bf16x8*)(smem + slotR + 32768 + bRd + n * 1024);
      bgK1[n] = *(const bf16x8*)(smem + slotR + 32768 + 16384 + bRd + n * 1024);
    }

    __builtin_amdgcn_s_setprio(1);
#pragma unroll
    for (int h = 0; h < 2; ++h) {
#pragma unroll
      for (int mi = 0; mi < 4; ++mi) {
        const bf16x8 a0 = *(const bf16x8*)(smem + slotR + h * 16384 + aRd +
                                           mi * 2048 + aSw0);
        const bf16x8 a1 = *(const bf16x8*)(smem + slotR + h * 16384 + aRd +
                                           mi * 2048 + aSw1);
#pragma unroll
        for (int n = 0; n < 8; ++n)
          acc[h * 4 + mi][n] = __builtin_amdgcn_mfma_f32_16x16x32_bf16(
              a0, bgK0[n], acc[h * 4 + mi][n], 0, 0, 0);
#pragma unroll
        for (int n = 0; n < 8; ++n)
          acc[h * 4 + mi][n] = __builtin_amdgcn_mfma_f32_16x16x32_bf16(
              a1, bgK1[n], acc[h * 4 + mi][n], 0, 0, 0);
      }
    }
    __builtin_amdgcn_s_setprio(0);

    if (st) {
      asm volatile("s_waitcnt vmcnt(0)");
      __builtin_amdgcn_s_barrier();
    }
  }

  // ---- epilogue: density partials for this wave's 128x128 output ----
  f32x4 xrv[8];
#pragma unroll
  for (int m = 0; m < 8; ++m)
    xrv[m] = *(const f32x4*)(xsq + rowBase + wr * 128 + m * 16 + lc * 4);

  float rsum[8][4];
#pragma unroll
  for (int m = 0; m < 8; ++m)
#pragma unroll
    for (int j = 0; j < 4; ++j) rsum[m][j] = 0.f;

#pragma unroll
  for (int n = 0; n < 8; ++n) {
    const int gc = colBase + wcn * 128 + n * 16 + lr;
    const float cs = csq[gc];
    const float ww = w[gc];
#pragma unroll
    for (int m = 0; m < 8; ++m)
#pragma unroll
      for (int j = 0; j < 4; ++j) {
        const float sq = xrv[m][j] + cs - 2.f * acc[m][n][j];
        rsum[m][j] += ww * __builtin_amdgcn_rcpf(sq);
      }
  }
#pragma unroll
  for (int m = 0; m < 8; ++m)
#pragma unroll
    for (int j = 0; j < 4; ++j) {
      float v = rsum[m][j];
      v += __shfl_xor(v, 1, 64);
      v += __shfl_xor(v, 2, 64);
      v += __shfl_xor(v, 4, 64);
      v += __shfl_xor(v, 8, 64);
      rsum[m][j] = v;
    }

  float* part = (float*)(smem + PART_OFF);   // [2 wcn][256 rows]
  __syncthreads();
  if (lr == 0) {
#pragma unroll
    for (int m = 0; m < 8; ++m)
#pragma unroll
      for (int j = 0; j < 4; ++j)
        part[wcn * 256 + wr * 128 + m * 16 + lc * 4 + j] = rsum[m][j];
  }
  __syncthreads();
  if (tid < BM) {
    const float s = part[tid] + part[256 + tid];
    partial[(size_t)ntile * NR + rowBase + tid] = s;
  }
}

// ---------------------------------------------------------------------------
__global__ __launch_bounds__(256) void reduce_kernel(
    const float* __restrict__ partial, const float* __restrict__ thr,
    float* __restrict__ out) {
  const int n = (int)(blockIdx.x * 256 + threadIdx.x);
  float s = 0.f;
#pragma unroll
  for (int g = 0; g < NPART; ++g) s += partial[(size_t)g * NR + n];
  out[n] = s - thr[0];
}

// ---------------------------------------------------------------------------
extern "C" void kernel_launch(void* const* d_in, const int* in_sizes, int n_in,
                              void* d_out, int out_size, void* d_ws, size_t ws_size,
                              hipStream_t stream) {
  const float* X   = (const float*)d_in[0];
  const float* C   = (const float*)d_in[1];
  const float* var = (const float*)d_in[2];
  const float* pr  = (const float*)d_in[3];
  const float* thr = (const float*)d_in[4];
  float* out = (float*)d_out;

  char* ws = (char*)d_ws;
  bf16* Xb   = (bf16*)(ws);
  bf16* Cb   = (bf16*)(ws + (size_t)NR * DD * 2);
  float* xsq = (float*)(ws + (size_t)NR * DD * 2 + (size_t)KC * DD * 2);
  float* csq = xsq + NR;
  float* w   = csq + KC;
  float* partial = w + KC;   // 4 * 65536 floats = 1 MB

  prep_kernel<<<(NR + KC) / 4, 256, 0, stream>>>(X, C, var, pr, Xb, Cb, xsq, csq, w);
  density_kernel<<<(NR / BM) * NPART, 256, LDS_TOTAL, stream>>>(
      Xb, Cb, xsq, csq, w, partial);
  reduce_kernel<<<NR / 256, 256, 0, stream>>>(partial, thr, out);
}

// Round 8
// 145.672 us; speedup vs baseline: 1.1006x; 1.1006x over previous
//
#include <hip/hip_runtime.h>
#include <stdint.h>

// ---------------------------------------------------------------------------
// DetectorKmeans: out[n] = sum_k (pr[k]*var[k]) / ||X[n]-C[k]||^2  - threshold
// N=65536, K=1024, D=512, all fp32 in/out.
// Round 20: B bypasses LDS. Cb is 1 MB = L2-resident on every XCD, and the
// B-panel has no LDS reuse worth the port traffic (stage 32 KB + read 64 KB
// per tile). B fragments now load straight from L2 into the same registers
// via coalesced global_load_dwordx4 (16 lanes x 64B lines); LDS is A-only
// (32 KB slots, double-buffered, 68 KB total). Per-tile LDS-port work drops
// 2760 -> ~1750 cyc, staging DMA halves, and the tile-end vmcnt(0) now waits
// on 4 A-loads issued a full MFMA-cluster earlier. A path, swizzles,
// schedule, epilogue, prep: verbatim R12 (proven, 0 conflicts).
// ---------------------------------------------------------------------------

#define NR 65536
#define KC 1024
#define DD 512

#define BM 256
#define BN 256
#define BK 64
#define NKT (DD / BK)     // 8 K-tiles
#define NPART (KC / BN)   // 4 column panels

#define SLOT_SZ 32768     // A-only: 256 rows x 128 B
#define PART_OFF 65536    // after 2 slots
#define LDS_TOTAL (PART_OFF + 4096)   // + [4][256] f32 partial = 69632 B

typedef __bf16 bf16;
typedef __attribute__((ext_vector_type(4))) __bf16 bf16x4;
typedef __attribute__((ext_vector_type(8))) __bf16 bf16x8;
typedef __attribute__((ext_vector_type(4))) float f32x4;

__device__ __forceinline__ void gload16(const void* g, void* l) {
  __builtin_amdgcn_global_load_lds(
      (const __attribute__((address_space(1))) unsigned int*)g,
      (__attribute__((address_space(3))) unsigned int*)l, 16, 0, 0);
}

// ---------------------------------------------------------------------------
__global__ __launch_bounds__(256) void prep_kernel(
    const float* __restrict__ X, const float* __restrict__ C,
    const float* __restrict__ var, const float* __restrict__ pr,
    bf16* __restrict__ Xb, bf16* __restrict__ Cb,
    float* __restrict__ xsq, float* __restrict__ csq, float* __restrict__ w) {
  const int row  = (int)((blockIdx.x * 256 + threadIdx.x) >> 6);
  const int lane = (int)(threadIdx.x & 63);
  const bool isX = row < NR;
  const float* srow = isX ? (X + (size_t)row * DD) : (C + (size_t)(row - NR) * DD);
  bf16* drow = isX ? (Xb + (size_t)row * DD) : (Cb + (size_t)(row - NR) * DD);

  float4 a = reinterpret_cast<const float4*>(srow)[lane];
  float4 b = reinterpret_cast<const float4*>(srow)[64 + lane];
  float s = a.x * a.x + a.y * a.y + a.z * a.z + a.w * a.w +
            b.x * b.x + b.y * b.y + b.z * b.z + b.w * b.w;
#pragma unroll
  for (int off = 1; off < 64; off <<= 1) s += __shfl_xor(s, off, 64);

  bf16x4 va = {(bf16)a.x, (bf16)a.y, (bf16)a.z, (bf16)a.w};
  bf16x4 vb = {(bf16)b.x, (bf16)b.y, (bf16)b.z, (bf16)b.w};
  reinterpret_cast<bf16x4*>(drow)[lane]      = va;
  reinterpret_cast<bf16x4*>(drow)[64 + lane] = vb;

  if (lane == 0) {
    if (isX) {
      xsq[row] = s;
    } else {
      const int k = row - NR;
      csq[k] = s;
      w[k]   = pr[k] * var[k];
    }
  }
}

// ---------------------------------------------------------------------------
// LDS per 32 KB slot (A only, layout verbatim R12):
//   A half h at slot + h*16384: rows {wr*128 + h*64 + r} at rho = wr*64+r,
//     128 B/row; chunk slot s holds global chunk s ^ (rho&7).
//   Pre-swizzled gload source, linear DMA dest.
// ---------------------------------------------------------------------------

#define STAGE_A(h, tn, slotW)                                                   \
  gload16(aSrc0 + (size_t)((h) * 64) * DD + (tn) * 64,                          \
          smem + (slotW) + (h) * 16384 + wid * 1024);                           \
  gload16(aSrc0 + (size_t)((h) * 64 + 128) * DD + (tn) * 64,                    \
          smem + (slotW) + (h) * 16384 + 8192 + wid * 1024);

__global__ __launch_bounds__(512, 2) void density_kernel(
    const bf16* __restrict__ Xb, const bf16* __restrict__ Cb,
    const float* __restrict__ xsq, const float* __restrict__ csq,
    const float* __restrict__ w, float* __restrict__ partial) {
  extern __shared__ char smem[];

  const int tid  = (int)threadIdx.x;
  const int lane = tid & 63;
  const int wid  = tid >> 6;    // 0..7
  const int wr   = wid >> 2;    // 0..1 : 128-row half
  const int wcn  = wid & 3;     // 0..3 : 64-col group
  const int lr   = lane & 15;
  const int lc   = lane >> 4;

  // XCD-aware bijective swizzle: grid 1024, 8 XCDs, 128 blocks each.
  const int bid   = (int)blockIdx.x;
  const int swz   = (bid & 7) * 128 + (bid >> 3);
  const int ntile = swz >> 8;
  const int mtile = swz & 255;
  const int rowBase = mtile * BM;
  const int colBase = ntile * BN;

  // A staging source (pre-swizzled chunk; linear DMA dest) — verbatim R12
  const bf16* aSrc0 = Xb + (size_t)(rowBase + wid * 8 + (lane >> 3)) * DD +
                      (((lane & 7) ^ (lane >> 3)) << 3);

  // B fragment source: direct from L2-resident Cb. Lane's 16 B reproduces
  // the MFMA B-frag: col = colBase + wcn*64 + n*16 + lr, k = t*64+kk*32+lc*8.
  const bf16* bCol = Cb + (size_t)(colBase + wcn * 64 + lr) * DD + lc * 8;

  // A fragment read bases (same XOR on the read side) — verbatim R12
  const int aRd  = (wr * 64 + lr) * 128;
  const int aSw0 = ((lc ^ (lr & 7)) << 4);
  const int aSw1 = (((4 | lc) ^ (lr & 7)) << 4);

  f32x4 acc[8][4];
#pragma unroll
  for (int m = 0; m < 8; ++m)
#pragma unroll
    for (int n = 0; n < 4; ++n) acc[m][n] = (f32x4){0.f, 0.f, 0.f, 0.f};

  // ---- prologue: stage A tile 0 into slot 0 ----
  STAGE_A(0, 0, 0);
  STAGE_A(1, 0, 0);
  asm volatile("s_waitcnt vmcnt(0)");
  __builtin_amdgcn_s_barrier();

  // ---- main loop: one phase + one barrier per K-tile (R12 proven) ----
#pragma unroll 1
  for (int t = 0; t < NKT; ++t) {
    const int slotR = (t & 1) << 15;
    const int slotW = slotR ^ SLOT_SZ;
    const int tn = t + 1;
    const bool st = tn < NKT;

    // B fragments: 8 coalesced global loads from L2 (issued first for cover;
    // compiler inserts the counted vmcnt before first MFMA use)
    bf16x8 bgK0[4], bgK1[4];
#pragma unroll
    for (int n = 0; n < 4; ++n) {
      const bf16* bn = bCol + (size_t)n * 16 * DD + t * 64;
      bgK0[n] = *(const bf16x8*)(bn);
      bgK1[n] = *(const bf16x8*)(bn + 32);
    }

    // stage A of t+1 (4 gload_lds; full MFMA cluster of cover before vmcnt)
    if (st) {
      STAGE_A(0, tn, slotW);
      STAGE_A(1, tn, slotW);
    }

    // stream A-frag pairs; compiler inserts counted lgkm/vm waits
    __builtin_amdgcn_s_setprio(1);
#pragma unroll
    for (int h = 0; h < 2; ++h) {
#pragma unroll
      for (int mi = 0; mi < 4; ++mi) {
        const bf16x8 a0 = *(const bf16x8*)(smem + slotR + h * 16384 + aRd +
                                           mi * 2048 + aSw0);
        const bf16x8 a1 = *(const bf16x8*)(smem + slotR + h * 16384 + aRd +
                                           mi * 2048 + aSw1);
#pragma unroll
        for (int n = 0; n < 4; ++n)
          acc[h * 4 + mi][n] = __builtin_amdgcn_mfma_f32_16x16x32_bf16(
              a0, bgK0[n], acc[h * 4 + mi][n], 0, 0, 0);
#pragma unroll
        for (int n = 0; n < 4; ++n)
          acc[h * 4 + mi][n] = __builtin_amdgcn_mfma_f32_16x16x32_bf16(
              a1, bgK1[n], acc[h * 4 + mi][n], 0, 0, 0);
      }
    }
    __builtin_amdgcn_s_setprio(0);

    if (st) {
      asm volatile("s_waitcnt vmcnt(0)");   // A-stage landed (B already used)
      __builtin_amdgcn_s_barrier();         // the ONLY barrier per K-tile
    }
  }

  // ---- epilogue: density partials for this wave's 128x64 output ----
  float xr[8][4];
#pragma unroll
  for (int m = 0; m < 8; ++m)
#pragma unroll
    for (int j = 0; j < 4; ++j)
      xr[m][j] = xsq[rowBase + wr * 128 + m * 16 + lc * 4 + j];

  float rsum[8][4];
#pragma unroll
  for (int m = 0; m < 8; ++m)
#pragma unroll
    for (int j = 0; j < 4; ++j) rsum[m][j] = 0.f;

#pragma unroll
  for (int n = 0; n < 4; ++n) {
    const int gc = colBase + wcn * 64 + n * 16 + lr;
    const float cs = csq[gc];
    const float ww = w[gc];
#pragma unroll
    for (int m = 0; m < 8; ++m)
#pragma unroll
      for (int j = 0; j < 4; ++j) {
        const float sq = xr[m][j] + cs - 2.f * acc[m][n][j];
        rsum[m][j] += ww * __builtin_amdgcn_rcpf(sq);
      }
  }
#pragma unroll
  for (int m = 0; m < 8; ++m)
#pragma unroll
    for (int j = 0; j < 4; ++j) {
      float v = rsum[m][j];
      v += __shfl_xor(v, 1, 64);
      v += __shfl_xor(v, 2, 64);
      v += __shfl_xor(v, 4, 64);
      v += __shfl_xor(v, 8, 64);
      rsum[m][j] = v;
    }

  float* part = (float*)(smem + PART_OFF);   // [4 wcn][256 rows]
  __syncthreads();
  if (lr == 0) {
#pragma unroll
    for (int m = 0; m < 8; ++m)
#pragma unroll
      for (int j = 0; j < 4; ++j)
        part[wcn * 256 + wr * 128 + m * 16 + lc * 4 + j] = rsum[m][j];
  }
  __syncthreads();
  if (tid < BM) {
    const float s = part[tid] + part[256 + tid] + part[512 + tid] + part[768 + tid];
    partial[(size_t)ntile * NR + rowBase + tid] = s;
  }
}

// ---------------------------------------------------------------------------
__global__ __launch_bounds__(256) void reduce_kernel(
    const float* __restrict__ partial, const float* __restrict__ thr,
    float* __restrict__ out) {
  const int n = (int)(blockIdx.x * 256 + threadIdx.x);
  float s = 0.f;
#pragma unroll
  for (int g = 0; g < NPART; ++g) s += partial[(size_t)g * NR + n];
  out[n] = s - thr[0];
}

// ---------------------------------------------------------------------------
extern "C" void kernel_launch(void* const* d_in, const int* in_sizes, int n_in,
                              void* d_out, int out_size, void* d_ws, size_t ws_size,
                              hipStream_t stream) {
  const float* X   = (const float*)d_in[0];
  const float* C   = (const float*)d_in[1];
  const float* var = (const float*)d_in[2];
  const float* pr  = (const float*)d_in[3];
  const float* thr = (const float*)d_in[4];
  float* out = (float*)d_out;

  char* ws = (char*)d_ws;
  bf16* Xb   = (bf16*)(ws);
  bf16* Cb   = (bf16*)(ws + (size_t)NR * DD * 2);
  float* xsq = (float*)(ws + (size_t)NR * DD * 2 + (size_t)KC * DD * 2);
  float* csq = xsq + NR;
  float* w   = csq + KC;
  float* partial = w + KC;   // 4 * 65536 floats = 1 MB

  prep_kernel<<<(NR + KC) / 4, 256, 0, stream>>>(X, C, var, pr, Xb, Cb, xsq, csq, w);
  density_kernel<<<(NR / BM) * NPART, 512, LDS_TOTAL, stream>>>(
      Xb, Cb, xsq, csq, w, partial);
  reduce_kernel<<<NR / 256, 256, 0, stream>>>(partial, thr, out);
}